// Round 1
// baseline (951.329 us; speedup 1.0000x reference)
//
#include <hip/hip_runtime.h>
#include <math.h>

#define FDIM   128
#define TWOF   256
#define NRBF_  20
#define INDIM  276
#define K1PAD  288          // INDIM padded to multiple of 32
#define XS     296          // shared-buffer row stride in bf16 (odd # of 16B chunks)
#define TE     32           // edges per workgroup (32 -> 19.8KB LDS -> 8 blocks/CU)
#define ET     (TE/16)      // M-tiles of 16 per wave

typedef __bf16 bf16x8 __attribute__((ext_vector_type(8)));
typedef __bf16 bf16x4 __attribute__((ext_vector_type(4)));
typedef float  f32x4  __attribute__((ext_vector_type(4)));
typedef float  f32x2  __attribute__((ext_vector_type(2)));
typedef unsigned int u32x4v __attribute__((ext_vector_type(4)));

__device__ inline float blo(unsigned p){ return __uint_as_float(p << 16); }
__device__ inline float bhi(unsigned p){ return __uint_as_float(p & 0xffff0000u); }

// ---------------- helper kernels ----------------

__global__ void sniff_idx(const int* __restrict__ ei, int nsample, int* __restrict__ flag) {
    __shared__ int any;
    if (threadIdx.x == 0) any = 0;
    __syncthreads();
    int nz = 0;
    for (int i = threadIdx.x; i < nsample; i += blockDim.x)
        nz |= (ei[2 * i + 1] != 0);
    if (nz) atomicOr(&any, 1);
    __syncthreads();
    if (threadIdx.x == 0) *flag = any;
}

__global__ void init_out(const float4* __restrict__ s4, const float4* __restrict__ v4,
                         float4* __restrict__ out4, int nf4, int total4) {
    for (int i = blockIdx.x * blockDim.x + threadIdx.x; i < total4;
         i += gridDim.x * blockDim.x)
        out4[i] = (i < nf4) ? s4[i] : v4[i - nf4];
}

__global__ void prep_weights(const float* __restrict__ W1, const float* __restrict__ W2,
                             const float* __restrict__ Ws, const float* __restrict__ Wv,
                             __bf16* __restrict__ W1t, __bf16* __restrict__ W2t,
                             __bf16* __restrict__ W3t) {
    int id = blockIdx.x * 256 + threadIdx.x;
    const int n1 = 256 * K1PAD;
    if (id < n1) {
        int n = id / K1PAD, k = id - n * K1PAD;
        W1t[id] = (k < INDIM) ? (__bf16)W1[k * TWOF + n] : (__bf16)0.f;
    } else if (id < n1 + 65536) {
        int j = id - n1; int n = j >> 8, k = j & 255;
        W2t[j] = (__bf16)W2[k * TWOF + n];
    } else if (id < n1 + 131072) {
        int j = id - n1 - 65536; int n = j >> 8, k = j & 255;
        W3t[j] = (n < FDIM) ? (__bf16)Ws[k * FDIM + n]
                            : (__bf16)Wv[k * FDIM + (n - FDIM)];
    }
}

// ---------------- CSR build ----------------

__global__ void zero_hist(int* __restrict__ hist, int N) {
    int i = blockIdx.x * 256 + threadIdx.x;
    if (i < N) hist[i] = 0;
}

__global__ void hist_k(const int* __restrict__ ei, const int* __restrict__ flag,
                       int* __restrict__ hist, int E) {
    int e = blockIdx.x * 256 + threadIdx.x;
    if (e >= E) return;
    int dst = (*flag == 0) ? ei[2 * (E + e)] : ei[E + e];
    atomicAdd(&hist[dst], 1);
}

__global__ void scan_a(const int* __restrict__ hist, int* __restrict__ loc,
                       int* __restrict__ bsum, int N) {
    __shared__ int sums[256];
    int t = threadIdx.x;
    int base = blockIdx.x * 1024 + t * 4;
    int v0 = (base + 0 < N) ? hist[base + 0] : 0;
    int v1 = (base + 1 < N) ? hist[base + 1] : 0;
    int v2 = (base + 2 < N) ? hist[base + 2] : 0;
    int v3 = (base + 3 < N) ? hist[base + 3] : 0;
    int s = v0 + v1 + v2 + v3;
    sums[t] = s;
    __syncthreads();
    for (int off = 1; off < 256; off <<= 1) {
        int x = (t >= off) ? sums[t - off] : 0;
        __syncthreads();
        sums[t] += x;
        __syncthreads();
    }
    int excl = sums[t] - s;
    if (t == 255) bsum[blockIdx.x] = sums[255];
    if (base + 0 < N) loc[base + 0] = excl; excl += v0;
    if (base + 1 < N) loc[base + 1] = excl; excl += v1;
    if (base + 2 < N) loc[base + 2] = excl; excl += v2;
    if (base + 3 < N) loc[base + 3] = excl;
}

__global__ void scan_b(int* __restrict__ bsum, int nb) {
    if (threadIdx.x == 0 && blockIdx.x == 0) {
        int run = 0;
        for (int i = 0; i < nb; ++i) { int v = bsum[i]; bsum[i] = run; run += v; }
    }
}

__global__ void scan_c(const int* __restrict__ loc, const int* __restrict__ bsum,
                       int* __restrict__ rs, int* __restrict__ cursor, int N, int E) {
    int i = blockIdx.x * 256 + threadIdx.x;
    if (i < N) {
        int v = loc[i] + bsum[i >> 10];
        rs[i] = v; cursor[i] = v;
    }
    if (i == 0) rs[N] = E;
}

// store edge -> CSR slot (perm), not slot -> edge
__global__ void scatter_k(const int* __restrict__ ei, const int* __restrict__ flag,
                          int* __restrict__ cursor, int* __restrict__ perm, int E) {
    int e = blockIdx.x * 256 + threadIdx.x;
    if (e >= E) return;
    int dst = (*flag == 0) ? ei[2 * (E + e)] : ei[E + e];
    int pos = atomicAdd(&cursor[dst], 1);
    perm[e] = pos;
}

// ---------------- main edge kernel ----------------
// Single LDS buffer Sb holds X (L1 input), then H (L1/L2 output), then EO staging.
// TE=32: 19.8KB LDS/block -> 8 blocks/CU -> 32 waves/CU (8/SIMD) for latency hiding.

template<int CSR>
__launch_bounds__(256, 8)
__global__ void edge_kernel(const float* __restrict__ s,
                            const float* __restrict__ pos,
                            const int* __restrict__ ei,
                            const float* __restrict__ b1, const float* __restrict__ b2,
                            const float* __restrict__ bsm, const float* __restrict__ bvm,
                            const float* __restrict__ centers, const float* __restrict__ widths,
                            const __bf16* __restrict__ W1t, const __bf16* __restrict__ W2t,
                            const __bf16* __restrict__ W3t,
                            const int* __restrict__ flag,
                            const int* __restrict__ perm,
                            __bf16* __restrict__ EO,
                            float* __restrict__ dirx, float* __restrict__ diry,
                            float* __restrict__ dirz,
                            float* __restrict__ out, int N, int E) {
    __shared__ __align__(16) __bf16 Sb[TE][XS];
    __shared__ float sdir[3][TE];
    __shared__ int ssrc[TE], sdst[TE], svalid[TE], sperm[TE];

    const int t    = threadIdx.x;
    const int lane = t & 63;
    const int wave = t >> 6;
    const int e0   = blockIdx.x * TE;
    const int i64  = (*flag == 0);

    // ---- Phase A: per-edge prep
    if (t < TE) {
        int e = e0 + t;
        int valid = (e < E);
        int srcn = 0, dstn = 0;
        if (valid) {
            if (i64) { srcn = ei[2 * e]; dstn = ei[2 * (E + e)]; }
            else     { srcn = ei[e];     dstn = ei[E + e]; }
        }
        ssrc[t] = srcn; sdst[t] = dstn; svalid[t] = valid;
        float rx = pos[dstn * 3 + 0] - pos[srcn * 3 + 0];
        float ry = pos[dstn * 3 + 1] - pos[srcn * 3 + 1];
        float rz = pos[dstn * 3 + 2] - pos[srcn * 3 + 2];
        float dist = sqrtf(rx * rx + ry * ry + rz * rz);
        float inv = dist > 0.f ? 1.f / dist : 0.f;
        float dx = rx * inv, dy = ry * inv, dz = rz * inv;
        sdir[0][t] = dx; sdir[1][t] = dy; sdir[2][t] = dz;
        int p = 0;
        if (CSR && valid) {
            p = perm[e];
            __builtin_nontemporal_store(dx, &dirx[p]);
            __builtin_nontemporal_store(dy, &diry[p]);
            __builtin_nontemporal_store(dz, &dirz[p]);
        }
        sperm[t] = p;
#pragma unroll
        for (int k = 0; k < 32; ++k) {
            float val = 0.f;
            if (k < NRBF_) {
                float u = (dist - centers[k]) / (widths[k] + 1e-8f);
                val = __expf(-u * u);
            }
            Sb[t][TWOF + k] = (__bf16)val;
        }
    }
    __syncthreads();

    // ---- Phase B: gather s[src]/s[dst] -> X cols 0..255
    {
        const int half = lane >> 5;
        const int q    = lane & 31;
        const float4* s4 = (const float4*)s;
#pragma unroll 4
        for (int i = 0; i < TE / 4; ++i) {
            int e = wave * (TE / 4) + i;
            int node = half ? sdst[e] : ssrc[e];
            float4 x = s4[node * 32 + q];
            bf16x4 b; b.x = (__bf16)x.x; b.y = (__bf16)x.y; b.z = (__bf16)x.z; b.w = (__bf16)x.w;
            *(bf16x4*)&Sb[e][half * FDIM + q * 4] = b;
        }
    }
    __syncthreads();

    const int l15 = lane & 15;
    const int kg  = (lane >> 4) * 8;
    const int nbase = wave * 64;

    f32x4 acc[ET][4];

    // ================= Layer 1: K=288 (reads X) =================
#pragma unroll
    for (int et = 0; et < ET; ++et)
#pragma unroll
        for (int nt = 0; nt < 4; ++nt) acc[et][nt] = (f32x4)0.f;
    {
        const __bf16* bp[4];
#pragma unroll
        for (int nt = 0; nt < 4; ++nt)
            bp[nt] = &W1t[(size_t)(nbase + nt * 16 + l15) * K1PAD + kg];
        bf16x8 bcur[4];
#pragma unroll
        for (int nt = 0; nt < 4; ++nt) bcur[nt] = *(const bf16x8*)bp[nt];
#pragma unroll
        for (int kc = 0; kc < K1PAD; kc += 32) {
            bf16x8 bnxt[4];
            if (kc + 32 < K1PAD) {
#pragma unroll
                for (int nt = 0; nt < 4; ++nt)
                    bnxt[nt] = *(const bf16x8*)(bp[nt] + kc + 32);
            }
            bf16x8 a[ET];
#pragma unroll
            for (int et = 0; et < ET; ++et)
                a[et] = *(const bf16x8*)&Sb[et * 16 + l15][kc + kg];
#pragma unroll
            for (int nt = 0; nt < 4; ++nt)
#pragma unroll
                for (int et = 0; et < ET; ++et)
                    acc[et][nt] = __builtin_amdgcn_mfma_f32_16x16x32_bf16(a[et], bcur[nt], acc[et][nt], 0, 0, 0);
#pragma unroll
            for (int nt = 0; nt < 4; ++nt) bcur[nt] = bnxt[nt];
        }
    }
    __syncthreads();   // all X reads complete before H overwrites the buffer
#pragma unroll
    for (int nt = 0; nt < 4; ++nt) {
        int n = nbase + nt * 16 + l15;
        float bb = b1[n];
#pragma unroll
        for (int et = 0; et < ET; ++et)
#pragma unroll
            for (int r = 0; r < 4; ++r) {
                int m = et * 16 + (lane >> 4) * 4 + r;
                float h = acc[et][nt][r] + bb;
                Sb[m][n] = (__bf16)(h * __builtin_amdgcn_rcpf(1.f + __expf(-h)));
            }
    }
    __syncthreads();

    // ================= Layer 2: K=256 (reads H, rewrites H) =================
#pragma unroll
    for (int et = 0; et < ET; ++et)
#pragma unroll
        for (int nt = 0; nt < 4; ++nt) acc[et][nt] = (f32x4)0.f;
    {
        const __bf16* bp[4];
#pragma unroll
        for (int nt = 0; nt < 4; ++nt)
            bp[nt] = &W2t[(size_t)(nbase + nt * 16 + l15) * TWOF + kg];
        bf16x8 bcur[4];
#pragma unroll
        for (int nt = 0; nt < 4; ++nt) bcur[nt] = *(const bf16x8*)bp[nt];
#pragma unroll
        for (int kc = 0; kc < TWOF; kc += 32) {
            bf16x8 bnxt[4];
            if (kc + 32 < TWOF) {
#pragma unroll
                for (int nt = 0; nt < 4; ++nt)
                    bnxt[nt] = *(const bf16x8*)(bp[nt] + kc + 32);
            }
            bf16x8 a[ET];
#pragma unroll
            for (int et = 0; et < ET; ++et)
                a[et] = *(const bf16x8*)&Sb[et * 16 + l15][kc + kg];
#pragma unroll
            for (int nt = 0; nt < 4; ++nt)
#pragma unroll
                for (int et = 0; et < ET; ++et)
                    acc[et][nt] = __builtin_amdgcn_mfma_f32_16x16x32_bf16(a[et], bcur[nt], acc[et][nt], 0, 0, 0);
#pragma unroll
            for (int nt = 0; nt < 4; ++nt) bcur[nt] = bnxt[nt];
        }
    }
    __syncthreads();   // all h1 reads complete before overwrite
#pragma unroll
    for (int nt = 0; nt < 4; ++nt) {
        int n = nbase + nt * 16 + l15;
        float bb = b2[n];
#pragma unroll
        for (int et = 0; et < ET; ++et)
#pragma unroll
            for (int r = 0; r < 4; ++r) {
                int m = et * 16 + (lane >> 4) * 4 + r;
                float h = acc[et][nt][r] + bb;
                Sb[m][n] = (__bf16)(h * __builtin_amdgcn_rcpf(1.f + __expf(-h)));
            }
    }
    __syncthreads();

    // ================= Layer 3: K=256 (reads H) =================
#pragma unroll
    for (int et = 0; et < ET; ++et)
#pragma unroll
        for (int nt = 0; nt < 4; ++nt) acc[et][nt] = (f32x4)0.f;
    {
        const __bf16* bp[4];
#pragma unroll
        for (int nt = 0; nt < 4; ++nt) {
            int rowbase = ((nt >= 2) ? FDIM : 0) + wave * 32 + (nt & 1) * 16 + l15;
            bp[nt] = &W3t[(size_t)rowbase * TWOF + kg];
        }
        bf16x8 bcur[4];
#pragma unroll
        for (int nt = 0; nt < 4; ++nt) bcur[nt] = *(const bf16x8*)bp[nt];
#pragma unroll
        for (int kc = 0; kc < TWOF; kc += 32) {
            bf16x8 bnxt[4];
            if (kc + 32 < TWOF) {
#pragma unroll
                for (int nt = 0; nt < 4; ++nt)
                    bnxt[nt] = *(const bf16x8*)(bp[nt] + kc + 32);
            }
            bf16x8 a[ET];
#pragma unroll
            for (int et = 0; et < ET; ++et)
                a[et] = *(const bf16x8*)&Sb[et * 16 + l15][kc + kg];
#pragma unroll
            for (int nt = 0; nt < 4; ++nt)
#pragma unroll
                for (int et = 0; et < ET; ++et)
                    acc[et][nt] = __builtin_amdgcn_mfma_f32_16x16x32_bf16(a[et], bcur[nt], acc[et][nt], 0, 0, 0);
#pragma unroll
            for (int nt = 0; nt < 4; ++nt) bcur[nt] = bnxt[nt];
        }
    }

    float b3v[4];
#pragma unroll
    for (int nt = 0; nt < 4; ++nt) {
        int n = wave * 32 + (nt & 1) * 16 + l15;
        b3v[nt] = (nt < 2) ? bsm[n] : bvm[n];
    }

    if (CSR) {
        __syncthreads();   // all H reads complete before EO staging overwrites buffer
        __bf16 (*EOs)[XS] = (__bf16(*)[XS])(&Sb[0][0]);
#pragma unroll
        for (int nt = 0; nt < 4; ++nt) {
            int col = ((nt >= 2) ? FDIM : 0) + wave * 32 + (nt & 1) * 16 + l15;
            float bb = b3v[nt];
#pragma unroll
            for (int et = 0; et < ET; ++et)
#pragma unroll
                for (int r = 0; r < 4; ++r) {
                    int m = et * 16 + (lane >> 4) * 4 + r;
                    EOs[m][col] = (__bf16)(acc[et][nt][r] + bb);
                }
        }
        __syncthreads();
        u32x4v* dst4 = (u32x4v*)EO;
#pragma unroll
        for (int j = 0; j < TE / 8; ++j) {
            int flat = j * 256 + t;          // 0..(TE*32-1)
            int row = flat >> 5, col = flat & 31;
            if (!svalid[row]) continue;
            __builtin_nontemporal_store(*(const u32x4v*)&EOs[row][col * 8],
                                        &dst4[(size_t)sperm[row] * 32 + col]);
        }
    } else {
        float* outs = out;
        float* outv = out + (size_t)N * FDIM;
#pragma unroll
        for (int et = 0; et < ET; ++et) {
#pragma unroll
            for (int r = 0; r < 4; ++r) {
                int m = et * 16 + (lane >> 4) * 4 + r;
                if (!svalid[m]) continue;
                int dst = sdst[m];
                float dx = sdir[0][m], dy = sdir[1][m], dz = sdir[2][m];
#pragma unroll
                for (int nt = 0; nt < 4; ++nt) {
                    int n = wave * 32 + (nt & 1) * 16 + l15;
                    float val = acc[et][nt][r] + b3v[nt];
                    if (nt < 2) {
                        atomicAdd(&outs[dst * FDIM + n], val);
                    } else {
                        int base = dst * 3 * FDIM + n;
                        atomicAdd(&outv[base],            dx * val);
                        atomicAdd(&outv[base + FDIM],     dy * val);
                        atomicAdd(&outv[base + 2 * FDIM], dz * val);
                    }
                }
            }
        }
    }
}

// ---------------- node aggregation: fully streaming (EO/dir pre-sorted) ----------------

__launch_bounds__(256)
__global__ void node_kernel(const float* __restrict__ s, const float* __restrict__ v,
                            const __bf16* __restrict__ EO,
                            const float* __restrict__ dirx, const float* __restrict__ diry,
                            const float* __restrict__ dirz,
                            const int* __restrict__ rs,
                            float* __restrict__ out, int N) {
    int wave = threadIdx.x >> 6, lane = threadIdx.x & 63;
    int n = blockIdx.x * 4 + wave;
    if (n >= N) return;
    int beg = rs[n], end = rs[n + 1];

    float a0 = 0.f, a1 = 0.f;
    float vx0 = 0.f, vx1 = 0.f, vy0 = 0.f, vy1 = 0.f, vz0 = 0.f, vz1 = 0.f;
    const unsigned* EO32 = (const unsigned*)EO;

#pragma unroll 2
    for (int i = beg; i < end; ++i) {
        unsigned pds = __builtin_nontemporal_load(&EO32[(size_t)i * 128 + lane]);
        unsigned pvm = __builtin_nontemporal_load(&EO32[(size_t)i * 128 + 64 + lane]);
        float dx = __builtin_nontemporal_load(&dirx[i]);
        float dy = __builtin_nontemporal_load(&diry[i]);
        float dz = __builtin_nontemporal_load(&dirz[i]);
        float d0 = blo(pds), d1 = bhi(pds);
        float m0 = blo(pvm), m1 = bhi(pvm);
        a0 += d0; a1 += d1;
        vx0 = fmaf(dx, m0, vx0); vx1 = fmaf(dx, m1, vx1);
        vy0 = fmaf(dy, m0, vy0); vy1 = fmaf(dy, m1, vy1);
        vz0 = fmaf(dz, m0, vz0); vz1 = fmaf(dz, m1, vz1);
    }

    f32x2 sv = *((const f32x2*)&s[(size_t)n * FDIM] + lane);
    f32x2 o0 = { sv.x + a0, sv.y + a1 };
    __builtin_nontemporal_store(o0, (f32x2*)&out[(size_t)n * FDIM] + lane);

    const float* vb = &v[(size_t)n * 3 * FDIM];
    float* ovb = &out[(size_t)N * FDIM + (size_t)n * 3 * FDIM];
    f32x2 vv;
    vv = *((const f32x2*)vb + lane);
    f32x2 ox = { vv.x + vx0, vv.y + vx1 };
    __builtin_nontemporal_store(ox, (f32x2*)ovb + lane);
    vv = *((const f32x2*)(vb + FDIM) + lane);
    f32x2 oy = { vv.x + vy0, vv.y + vy1 };
    __builtin_nontemporal_store(oy, (f32x2*)(ovb + FDIM) + lane);
    vv = *((const f32x2*)(vb + 2 * FDIM) + lane);
    f32x2 oz = { vv.x + vz0, vv.y + vz1 };
    __builtin_nontemporal_store(oz, (f32x2*)(ovb + 2 * FDIM) + lane);
}

// ---------------- host ----------------

static inline size_t align256(size_t x) { return (x + 255) & ~(size_t)255; }

extern "C" void kernel_launch(void* const* d_in, const int* in_sizes, int n_in,
                              void* d_out, int out_size, void* d_ws, size_t ws_size,
                              hipStream_t stream) {
    const float* s   = (const float*)d_in[0];
    const float* v   = (const float*)d_in[1];
    const float* pos = (const float*)d_in[2];
    const int*   ei  = (const int*)d_in[3];
    const float* W1  = (const float*)d_in[4];
    const float* b1  = (const float*)d_in[5];
    const float* W2  = (const float*)d_in[6];
    const float* b2  = (const float*)d_in[7];
    const float* Wsm = (const float*)d_in[8];
    const float* bsm = (const float*)d_in[9];
    const float* Wvm = (const float*)d_in[10];
    const float* bvm = (const float*)d_in[11];
    const float* centers = (const float*)d_in[12];
    const float* widths  = (const float*)d_in[13];
    float* out = (float*)d_out;

    int N = in_sizes[0] / FDIM;
    int E = in_sizes[3] / 2;
    int nblocks = (E + TE - 1) / TE;

    // workspace layout
    size_t off = 0;
    int* flag = (int*)((char*)d_ws + off);           off = align256(off + 4);
    __bf16* W1t = (__bf16*)((char*)d_ws + off);      off = align256(off + (size_t)256 * K1PAD * 2);
    __bf16* W2t = (__bf16*)((char*)d_ws + off);      off = align256(off + (size_t)256 * TWOF * 2);
    __bf16* W3t = (__bf16*)((char*)d_ws + off);      off = align256(off + (size_t)256 * TWOF * 2);
    int* hist   = (int*)((char*)d_ws + off);         off = align256(off + (size_t)N * 4);
    int* loc    = (int*)((char*)d_ws + off);         off = align256(off + (size_t)N * 4);
    int* bsum   = (int*)((char*)d_ws + off);         off = align256(off + 1024);
    int* rs     = (int*)((char*)d_ws + off);         off = align256(off + (size_t)(N + 1) * 4);
    int* cursor = (int*)((char*)d_ws + off);         off = align256(off + (size_t)N * 4);
    int* perm   = (int*)((char*)d_ws + off);         off = align256(off + (size_t)E * 4);
    float* dirx = (float*)((char*)d_ws + off);       off = align256(off + (size_t)E * 4);
    float* diry = (float*)((char*)d_ws + off);       off = align256(off + (size_t)E * 4);
    float* dirz = (float*)((char*)d_ws + off);       off = align256(off + (size_t)E * 4);
    __bf16* EO  = (__bf16*)((char*)d_ws + off);      off = align256(off + (size_t)E * 256 * 2);
    bool use_csr = (off <= ws_size);

    int nsample = E < 1024 ? E : 1024;
    hipLaunchKernelGGL(sniff_idx, dim3(1), dim3(256), 0, stream, ei, nsample, flag);

    int nprep = 256 * K1PAD + 2 * 256 * TWOF;
    hipLaunchKernelGGL(prep_weights, dim3((nprep + 255) / 256), dim3(256), 0, stream,
                       W1, W2, Wsm, Wvm, W1t, W2t, W3t);

    if (use_csr) {
        int nb = (N + 1023) / 1024;
        hipLaunchKernelGGL(zero_hist, dim3((N + 255) / 256), dim3(256), 0, stream, hist, N);
        hipLaunchKernelGGL(hist_k, dim3((E + 255) / 256), dim3(256), 0, stream, ei, flag, hist, E);
        hipLaunchKernelGGL(scan_a, dim3(nb), dim3(256), 0, stream, hist, loc, bsum, N);
        hipLaunchKernelGGL(scan_b, dim3(1), dim3(64), 0, stream, bsum, nb);
        hipLaunchKernelGGL(scan_c, dim3((N + 255) / 256), dim3(256), 0, stream, loc, bsum, rs, cursor, N, E);
        hipLaunchKernelGGL(scatter_k, dim3((E + 255) / 256), dim3(256), 0, stream, ei, flag, cursor, perm, E);

        hipLaunchKernelGGL(edge_kernel<1>, dim3(nblocks), dim3(256), 0, stream,
                           s, pos, ei, b1, b2, bsm, bvm, centers, widths,
                           W1t, W2t, W3t, flag, perm, EO, dirx, diry, dirz, out, N, E);

        hipLaunchKernelGGL(node_kernel, dim3((N + 3) / 4), dim3(256), 0, stream,
                           s, v, EO, dirx, diry, dirz, rs, out, N);
    } else {
        int nf4    = (N * FDIM) / 4;
        int total4 = N * FDIM;
        hipLaunchKernelGGL(init_out, dim3(8192), dim3(256), 0, stream,
                           (const float4*)s, (const float4*)v, (float4*)out, nf4, total4);
        hipLaunchKernelGGL(edge_kernel<0>, dim3(nblocks), dim3(256), 0, stream,
                           s, pos, ei, b1, b2, bsm, bvm, centers, widths,
                           W1t, W2t, W3t, flag, perm, EO, dirx, diry, dirz, out, N, E);
    }
}

// Round 2
// 833.497 us; speedup vs baseline: 1.1414x; 1.1414x over previous
//
#include <hip/hip_runtime.h>
#include <math.h>

#define FDIM   128
#define TWOF   256
#define NRBF_  20
#define INDIM  276
#define K1PAD  288          // INDIM padded to multiple of 32
#define XS     296          // shared-buffer row stride in bf16 (odd # of 16B chunks)
#define TE     128          // edges per workgroup (128 -> 79.4KB LDS -> 2 blocks/CU, 8 waves)
#define ET     4            // M-tiles of 16 per wave (TE / 2 wm-groups / 16)

typedef __bf16 bf16x8 __attribute__((ext_vector_type(8)));
typedef __bf16 bf16x4 __attribute__((ext_vector_type(4)));
typedef float  f32x4  __attribute__((ext_vector_type(4)));
typedef float  f32x2  __attribute__((ext_vector_type(2)));
typedef unsigned int u32x4v __attribute__((ext_vector_type(4)));

__device__ inline float blo(unsigned p){ return __uint_as_float(p << 16); }
__device__ inline float bhi(unsigned p){ return __uint_as_float(p & 0xffff0000u); }

// ---------------- helper kernels ----------------

__global__ void sniff_idx(const int* __restrict__ ei, int nsample, int* __restrict__ flag) {
    __shared__ int any;
    if (threadIdx.x == 0) any = 0;
    __syncthreads();
    int nz = 0;
    for (int i = threadIdx.x; i < nsample; i += blockDim.x)
        nz |= (ei[2 * i + 1] != 0);
    if (nz) atomicOr(&any, 1);
    __syncthreads();
    if (threadIdx.x == 0) *flag = any;
}

__global__ void init_out(const float4* __restrict__ s4, const float4* __restrict__ v4,
                         float4* __restrict__ out4, int nf4, int total4) {
    for (int i = blockIdx.x * blockDim.x + threadIdx.x; i < total4;
         i += gridDim.x * blockDim.x)
        out4[i] = (i < nf4) ? s4[i] : v4[i - nf4];
}

__global__ void prep_weights(const float* __restrict__ W1, const float* __restrict__ W2,
                             const float* __restrict__ Ws, const float* __restrict__ Wv,
                             __bf16* __restrict__ W1t, __bf16* __restrict__ W2t,
                             __bf16* __restrict__ W3t) {
    int id = blockIdx.x * 256 + threadIdx.x;
    const int n1 = 256 * K1PAD;
    if (id < n1) {
        int n = id / K1PAD, k = id - n * K1PAD;
        W1t[id] = (k < INDIM) ? (__bf16)W1[k * TWOF + n] : (__bf16)0.f;
    } else if (id < n1 + 65536) {
        int j = id - n1; int n = j >> 8, k = j & 255;
        W2t[j] = (__bf16)W2[k * TWOF + n];
    } else if (id < n1 + 131072) {
        int j = id - n1 - 65536; int n = j >> 8, k = j & 255;
        W3t[j] = (n < FDIM) ? (__bf16)Ws[k * FDIM + n]
                            : (__bf16)Wv[k * FDIM + (n - FDIM)];
    }
}

// ---------------- CSR build ----------------

__global__ void zero_hist(int* __restrict__ hist, int N) {
    int i = blockIdx.x * 256 + threadIdx.x;
    if (i < N) hist[i] = 0;
}

__global__ void hist_k(const int* __restrict__ ei, const int* __restrict__ flag,
                       int* __restrict__ hist, int E) {
    int e = blockIdx.x * 256 + threadIdx.x;
    if (e >= E) return;
    int dst = (*flag == 0) ? ei[2 * (E + e)] : ei[E + e];
    atomicAdd(&hist[dst], 1);
}

__global__ void scan_a(const int* __restrict__ hist, int* __restrict__ loc,
                       int* __restrict__ bsum, int N) {
    __shared__ int sums[256];
    int t = threadIdx.x;
    int base = blockIdx.x * 1024 + t * 4;
    int v0 = (base + 0 < N) ? hist[base + 0] : 0;
    int v1 = (base + 1 < N) ? hist[base + 1] : 0;
    int v2 = (base + 2 < N) ? hist[base + 2] : 0;
    int v3 = (base + 3 < N) ? hist[base + 3] : 0;
    int s = v0 + v1 + v2 + v3;
    sums[t] = s;
    __syncthreads();
    for (int off = 1; off < 256; off <<= 1) {
        int x = (t >= off) ? sums[t - off] : 0;
        __syncthreads();
        sums[t] += x;
        __syncthreads();
    }
    int excl = sums[t] - s;
    if (t == 255) bsum[blockIdx.x] = sums[255];
    if (base + 0 < N) loc[base + 0] = excl; excl += v0;
    if (base + 1 < N) loc[base + 1] = excl; excl += v1;
    if (base + 2 < N) loc[base + 2] = excl; excl += v2;
    if (base + 3 < N) loc[base + 3] = excl;
}

__global__ void scan_b(int* __restrict__ bsum, int nb) {
    if (threadIdx.x == 0 && blockIdx.x == 0) {
        int run = 0;
        for (int i = 0; i < nb; ++i) { int v = bsum[i]; bsum[i] = run; run += v; }
    }
}

__global__ void scan_c(const int* __restrict__ loc, const int* __restrict__ bsum,
                       int* __restrict__ rs, int* __restrict__ cursor, int N, int E) {
    int i = blockIdx.x * 256 + threadIdx.x;
    if (i < N) {
        int v = loc[i] + bsum[i >> 10];
        rs[i] = v; cursor[i] = v;
    }
    if (i == 0) rs[N] = E;
}

// store edge -> CSR slot (perm), not slot -> edge
__global__ void scatter_k(const int* __restrict__ ei, const int* __restrict__ flag,
                          int* __restrict__ cursor, int* __restrict__ perm, int E) {
    int e = blockIdx.x * 256 + threadIdx.x;
    if (e >= E) return;
    int dst = (*flag == 0) ? ei[2 * (E + e)] : ei[E + e];
    int pos = atomicAdd(&cursor[dst], 1);
    perm[e] = pos;
}

// ---------------- main edge kernel ----------------
// Single LDS buffer Sb holds X (L1 input), then H (L1/L2 output), then EO staging.
// TE=128 / 512 threads / 8 waves in a 2(M) x 4(N) grid:
//   - waves (wm=0,wn) and (wm=1,wn) stream the SAME B-weight rows -> L1 reuse,
//     halving L2 weight traffic per edge vs the TE=64 config.
//   - per-wave shape (ET=4 M-tiles x 4 N-tiles, acc[4][4]) identical to the
//     proven 494us config, so register/pipeline profile is preserved.
//   - LDS 79.4KB -> 2 blocks/CU -> 16 waves/CU (4/SIMD), same as 494us config.

template<int CSR>
__launch_bounds__(512, 4)
__global__ void edge_kernel(const float* __restrict__ s,
                            const float* __restrict__ pos,
                            const int* __restrict__ ei,
                            const float* __restrict__ b1, const float* __restrict__ b2,
                            const float* __restrict__ bsm, const float* __restrict__ bvm,
                            const float* __restrict__ centers, const float* __restrict__ widths,
                            const __bf16* __restrict__ W1t, const __bf16* __restrict__ W2t,
                            const __bf16* __restrict__ W3t,
                            const int* __restrict__ flag,
                            const int* __restrict__ perm,
                            __bf16* __restrict__ EO,
                            float* __restrict__ dirx, float* __restrict__ diry,
                            float* __restrict__ dirz,
                            float* __restrict__ out, int N, int E) {
    __shared__ __align__(16) __bf16 Sb[TE][XS];
    __shared__ float sdir[3][TE];
    __shared__ int ssrc[TE], sdst[TE], svalid[TE], sperm[TE];

    const int t    = threadIdx.x;
    const int lane = t & 63;
    const int wave = t >> 6;
    const int wm   = wave >> 2;        // 0..1 : which 64-edge half
    const int wn   = wave & 3;         // 0..3 : which 64-col quarter
    const int e0   = blockIdx.x * TE;
    const int i64  = (*flag == 0);

    // ---- Phase A: per-edge prep
    if (t < TE) {
        int e = e0 + t;
        int valid = (e < E);
        int srcn = 0, dstn = 0;
        if (valid) {
            if (i64) { srcn = ei[2 * e]; dstn = ei[2 * (E + e)]; }
            else     { srcn = ei[e];     dstn = ei[E + e]; }
        }
        ssrc[t] = srcn; sdst[t] = dstn; svalid[t] = valid;
        float rx = pos[dstn * 3 + 0] - pos[srcn * 3 + 0];
        float ry = pos[dstn * 3 + 1] - pos[srcn * 3 + 1];
        float rz = pos[dstn * 3 + 2] - pos[srcn * 3 + 2];
        float dist = sqrtf(rx * rx + ry * ry + rz * rz);
        float inv = dist > 0.f ? 1.f / dist : 0.f;
        float dx = rx * inv, dy = ry * inv, dz = rz * inv;
        sdir[0][t] = dx; sdir[1][t] = dy; sdir[2][t] = dz;
        int p = 0;
        if (CSR && valid) {
            p = perm[e];
            __builtin_nontemporal_store(dx, &dirx[p]);
            __builtin_nontemporal_store(dy, &diry[p]);
            __builtin_nontemporal_store(dz, &dirz[p]);
        }
        sperm[t] = p;
#pragma unroll
        for (int k = 0; k < 32; ++k) {
            float val = 0.f;
            if (k < NRBF_) {
                float u = (dist - centers[k]) / (widths[k] + 1e-8f);
                val = __expf(-u * u);
            }
            Sb[t][TWOF + k] = (__bf16)val;
        }
    }
    __syncthreads();

    // ---- Phase B: gather s[src]/s[dst] -> X cols 0..255 (16 edges per wave)
    {
        const int half = lane >> 5;
        const int q    = lane & 31;
        const float4* s4 = (const float4*)s;
#pragma unroll 4
        for (int i = 0; i < 16; ++i) {
            int e = wave * 16 + i;
            int node = half ? sdst[e] : ssrc[e];
            float4 x = s4[node * 32 + q];
            bf16x4 b; b.x = (__bf16)x.x; b.y = (__bf16)x.y; b.z = (__bf16)x.z; b.w = (__bf16)x.w;
            *(bf16x4*)&Sb[e][half * FDIM + q * 4] = b;
        }
    }
    __syncthreads();

    const int l15 = lane & 15;
    const int kg  = (lane >> 4) * 8;
    const int nbase = wn * 64;
    const int mbase = wm * 64;

    f32x4 acc[ET][4];

    // ================= Layer 1: K=288 (reads X) =================
#pragma unroll
    for (int et = 0; et < ET; ++et)
#pragma unroll
        for (int nt = 0; nt < 4; ++nt) acc[et][nt] = (f32x4)0.f;
    {
        const __bf16* bp[4];
#pragma unroll
        for (int nt = 0; nt < 4; ++nt)
            bp[nt] = &W1t[(size_t)(nbase + nt * 16 + l15) * K1PAD + kg];
        bf16x8 bcur[4];
#pragma unroll
        for (int nt = 0; nt < 4; ++nt) bcur[nt] = *(const bf16x8*)bp[nt];
#pragma unroll
        for (int kc = 0; kc < K1PAD; kc += 32) {
            bf16x8 bnxt[4];
            if (kc + 32 < K1PAD) {
#pragma unroll
                for (int nt = 0; nt < 4; ++nt)
                    bnxt[nt] = *(const bf16x8*)(bp[nt] + kc + 32);
            }
            bf16x8 a[ET];
#pragma unroll
            for (int et = 0; et < ET; ++et)
                a[et] = *(const bf16x8*)&Sb[mbase + et * 16 + l15][kc + kg];
#pragma unroll
            for (int nt = 0; nt < 4; ++nt)
#pragma unroll
                for (int et = 0; et < ET; ++et)
                    acc[et][nt] = __builtin_amdgcn_mfma_f32_16x16x32_bf16(a[et], bcur[nt], acc[et][nt], 0, 0, 0);
#pragma unroll
            for (int nt = 0; nt < 4; ++nt) bcur[nt] = bnxt[nt];
        }
    }
    __syncthreads();   // all X reads complete before H overwrites the buffer
#pragma unroll
    for (int nt = 0; nt < 4; ++nt) {
        int n = nbase + nt * 16 + l15;
        float bb = b1[n];
#pragma unroll
        for (int et = 0; et < ET; ++et)
#pragma unroll
            for (int r = 0; r < 4; ++r) {
                int m = mbase + et * 16 + (lane >> 4) * 4 + r;
                float h = acc[et][nt][r] + bb;
                Sb[m][n] = (__bf16)(h * __builtin_amdgcn_rcpf(1.f + __expf(-h)));
            }
    }
    __syncthreads();

    // ================= Layer 2: K=256 (reads H, rewrites H) =================
#pragma unroll
    for (int et = 0; et < ET; ++et)
#pragma unroll
        for (int nt = 0; nt < 4; ++nt) acc[et][nt] = (f32x4)0.f;
    {
        const __bf16* bp[4];
#pragma unroll
        for (int nt = 0; nt < 4; ++nt)
            bp[nt] = &W2t[(size_t)(nbase + nt * 16 + l15) * TWOF + kg];
        bf16x8 bcur[4];
#pragma unroll
        for (int nt = 0; nt < 4; ++nt) bcur[nt] = *(const bf16x8*)bp[nt];
#pragma unroll
        for (int kc = 0; kc < TWOF; kc += 32) {
            bf16x8 bnxt[4];
            if (kc + 32 < TWOF) {
#pragma unroll
                for (int nt = 0; nt < 4; ++nt)
                    bnxt[nt] = *(const bf16x8*)(bp[nt] + kc + 32);
            }
            bf16x8 a[ET];
#pragma unroll
            for (int et = 0; et < ET; ++et)
                a[et] = *(const bf16x8*)&Sb[mbase + et * 16 + l15][kc + kg];
#pragma unroll
            for (int nt = 0; nt < 4; ++nt)
#pragma unroll
                for (int et = 0; et < ET; ++et)
                    acc[et][nt] = __builtin_amdgcn_mfma_f32_16x16x32_bf16(a[et], bcur[nt], acc[et][nt], 0, 0, 0);
#pragma unroll
            for (int nt = 0; nt < 4; ++nt) bcur[nt] = bnxt[nt];
        }
    }
    __syncthreads();   // all h1 reads complete before overwrite
#pragma unroll
    for (int nt = 0; nt < 4; ++nt) {
        int n = nbase + nt * 16 + l15;
        float bb = b2[n];
#pragma unroll
        for (int et = 0; et < ET; ++et)
#pragma unroll
            for (int r = 0; r < 4; ++r) {
                int m = mbase + et * 16 + (lane >> 4) * 4 + r;
                float h = acc[et][nt][r] + bb;
                Sb[m][n] = (__bf16)(h * __builtin_amdgcn_rcpf(1.f + __expf(-h)));
            }
    }
    __syncthreads();

    // ================= Layer 3: K=256 (reads H) =================
#pragma unroll
    for (int et = 0; et < ET; ++et)
#pragma unroll
        for (int nt = 0; nt < 4; ++nt) acc[et][nt] = (f32x4)0.f;
    {
        const __bf16* bp[4];
#pragma unroll
        for (int nt = 0; nt < 4; ++nt) {
            int rowbase = ((nt >= 2) ? FDIM : 0) + wn * 32 + (nt & 1) * 16 + l15;
            bp[nt] = &W3t[(size_t)rowbase * TWOF + kg];
        }
        bf16x8 bcur[4];
#pragma unroll
        for (int nt = 0; nt < 4; ++nt) bcur[nt] = *(const bf16x8*)bp[nt];
#pragma unroll
        for (int kc = 0; kc < TWOF; kc += 32) {
            bf16x8 bnxt[4];
            if (kc + 32 < TWOF) {
#pragma unroll
                for (int nt = 0; nt < 4; ++nt)
                    bnxt[nt] = *(const bf16x8*)(bp[nt] + kc + 32);
            }
            bf16x8 a[ET];
#pragma unroll
            for (int et = 0; et < ET; ++et)
                a[et] = *(const bf16x8*)&Sb[mbase + et * 16 + l15][kc + kg];
#pragma unroll
            for (int nt = 0; nt < 4; ++nt)
#pragma unroll
                for (int et = 0; et < ET; ++et)
                    acc[et][nt] = __builtin_amdgcn_mfma_f32_16x16x32_bf16(a[et], bcur[nt], acc[et][nt], 0, 0, 0);
#pragma unroll
            for (int nt = 0; nt < 4; ++nt) bcur[nt] = bnxt[nt];
        }
    }

    float b3v[4];
#pragma unroll
    for (int nt = 0; nt < 4; ++nt) {
        int n = wn * 32 + (nt & 1) * 16 + l15;
        b3v[nt] = (nt < 2) ? bsm[n] : bvm[n];
    }

    if (CSR) {
        __syncthreads();   // all H reads complete before EO staging overwrites buffer
        __bf16 (*EOs)[XS] = (__bf16(*)[XS])(&Sb[0][0]);
#pragma unroll
        for (int nt = 0; nt < 4; ++nt) {
            int col = ((nt >= 2) ? FDIM : 0) + wn * 32 + (nt & 1) * 16 + l15;
            float bb = b3v[nt];
#pragma unroll
            for (int et = 0; et < ET; ++et)
#pragma unroll
                for (int r = 0; r < 4; ++r) {
                    int m = mbase + et * 16 + (lane >> 4) * 4 + r;
                    EOs[m][col] = (__bf16)(acc[et][nt][r] + bb);
                }
        }
        __syncthreads();
        u32x4v* dst4 = (u32x4v*)EO;
#pragma unroll
        for (int j = 0; j < (TE * 32) / 512; ++j) {
            int flat = j * 512 + t;          // 0..(TE*32-1)
            int row = flat >> 5, col = flat & 31;
            if (!svalid[row]) continue;
            __builtin_nontemporal_store(*(const u32x4v*)&EOs[row][col * 8],
                                        &dst4[(size_t)sperm[row] * 32 + col]);
        }
    } else {
        float* outs = out;
        float* outv = out + (size_t)N * FDIM;
#pragma unroll
        for (int et = 0; et < ET; ++et) {
#pragma unroll
            for (int r = 0; r < 4; ++r) {
                int m = mbase + et * 16 + (lane >> 4) * 4 + r;
                if (!svalid[m]) continue;
                int dst = sdst[m];
                float dx = sdir[0][m], dy = sdir[1][m], dz = sdir[2][m];
#pragma unroll
                for (int nt = 0; nt < 4; ++nt) {
                    int n = wn * 32 + (nt & 1) * 16 + l15;
                    float val = acc[et][nt][r] + b3v[nt];
                    if (nt < 2) {
                        atomicAdd(&outs[dst * FDIM + n], val);
                    } else {
                        int base = dst * 3 * FDIM + n;
                        atomicAdd(&outv[base],            dx * val);
                        atomicAdd(&outv[base + FDIM],     dy * val);
                        atomicAdd(&outv[base + 2 * FDIM], dz * val);
                    }
                }
            }
        }
    }
}

// ---------------- node aggregation: fully streaming (EO/dir pre-sorted) ----------------

__launch_bounds__(256)
__global__ void node_kernel(const float* __restrict__ s, const float* __restrict__ v,
                            const __bf16* __restrict__ EO,
                            const float* __restrict__ dirx, const float* __restrict__ diry,
                            const float* __restrict__ dirz,
                            const int* __restrict__ rs,
                            float* __restrict__ out, int N) {
    int wave = threadIdx.x >> 6, lane = threadIdx.x & 63;
    int n = blockIdx.x * 4 + wave;
    if (n >= N) return;
    int beg = rs[n], end = rs[n + 1];

    float a0 = 0.f, a1 = 0.f;
    float vx0 = 0.f, vx1 = 0.f, vy0 = 0.f, vy1 = 0.f, vz0 = 0.f, vz1 = 0.f;
    const unsigned* EO32 = (const unsigned*)EO;

#pragma unroll 2
    for (int i = beg; i < end; ++i) {
        unsigned pds = __builtin_nontemporal_load(&EO32[(size_t)i * 128 + lane]);
        unsigned pvm = __builtin_nontemporal_load(&EO32[(size_t)i * 128 + 64 + lane]);
        float dx = __builtin_nontemporal_load(&dirx[i]);
        float dy = __builtin_nontemporal_load(&diry[i]);
        float dz = __builtin_nontemporal_load(&dirz[i]);
        float d0 = blo(pds), d1 = bhi(pds);
        float m0 = blo(pvm), m1 = bhi(pvm);
        a0 += d0; a1 += d1;
        vx0 = fmaf(dx, m0, vx0); vx1 = fmaf(dx, m1, vx1);
        vy0 = fmaf(dy, m0, vy0); vy1 = fmaf(dy, m1, vy1);
        vz0 = fmaf(dz, m0, vz0); vz1 = fmaf(dz, m1, vz1);
    }

    f32x2 sv = *((const f32x2*)&s[(size_t)n * FDIM] + lane);
    f32x2 o0 = { sv.x + a0, sv.y + a1 };
    __builtin_nontemporal_store(o0, (f32x2*)&out[(size_t)n * FDIM] + lane);

    const float* vb = &v[(size_t)n * 3 * FDIM];
    float* ovb = &out[(size_t)N * FDIM + (size_t)n * 3 * FDIM];
    f32x2 vv;
    vv = *((const f32x2*)vb + lane);
    f32x2 ox = { vv.x + vx0, vv.y + vx1 };
    __builtin_nontemporal_store(ox, (f32x2*)ovb + lane);
    vv = *((const f32x2*)(vb + FDIM) + lane);
    f32x2 oy = { vv.x + vy0, vv.y + vy1 };
    __builtin_nontemporal_store(oy, (f32x2*)(ovb + FDIM) + lane);
    vv = *((const f32x2*)(vb + 2 * FDIM) + lane);
    f32x2 oz = { vv.x + vz0, vv.y + vz1 };
    __builtin_nontemporal_store(oz, (f32x2*)(ovb + 2 * FDIM) + lane);
}

// ---------------- host ----------------

static inline size_t align256(size_t x) { return (x + 255) & ~(size_t)255; }

extern "C" void kernel_launch(void* const* d_in, const int* in_sizes, int n_in,
                              void* d_out, int out_size, void* d_ws, size_t ws_size,
                              hipStream_t stream) {
    const float* s   = (const float*)d_in[0];
    const float* v   = (const float*)d_in[1];
    const float* pos = (const float*)d_in[2];
    const int*   ei  = (const int*)d_in[3];
    const float* W1  = (const float*)d_in[4];
    const float* b1  = (const float*)d_in[5];
    const float* W2  = (const float*)d_in[6];
    const float* b2  = (const float*)d_in[7];
    const float* Wsm = (const float*)d_in[8];
    const float* bsm = (const float*)d_in[9];
    const float* Wvm = (const float*)d_in[10];
    const float* bvm = (const float*)d_in[11];
    const float* centers = (const float*)d_in[12];
    const float* widths  = (const float*)d_in[13];
    float* out = (float*)d_out;

    int N = in_sizes[0] / FDIM;
    int E = in_sizes[3] / 2;
    int nblocks = (E + TE - 1) / TE;

    // workspace layout
    size_t off = 0;
    int* flag = (int*)((char*)d_ws + off);           off = align256(off + 4);
    __bf16* W1t = (__bf16*)((char*)d_ws + off);      off = align256(off + (size_t)256 * K1PAD * 2);
    __bf16* W2t = (__bf16*)((char*)d_ws + off);      off = align256(off + (size_t)256 * TWOF * 2);
    __bf16* W3t = (__bf16*)((char*)d_ws + off);      off = align256(off + (size_t)256 * TWOF * 2);
    int* hist   = (int*)((char*)d_ws + off);         off = align256(off + (size_t)N * 4);
    int* loc    = (int*)((char*)d_ws + off);         off = align256(off + (size_t)N * 4);
    int* bsum   = (int*)((char*)d_ws + off);         off = align256(off + 1024);
    int* rs     = (int*)((char*)d_ws + off);         off = align256(off + (size_t)(N + 1) * 4);
    int* cursor = (int*)((char*)d_ws + off);         off = align256(off + (size_t)N * 4);
    int* perm   = (int*)((char*)d_ws + off);         off = align256(off + (size_t)E * 4);
    float* dirx = (float*)((char*)d_ws + off);       off = align256(off + (size_t)E * 4);
    float* diry = (float*)((char*)d_ws + off);       off = align256(off + (size_t)E * 4);
    float* dirz = (float*)((char*)d_ws + off);       off = align256(off + (size_t)E * 4);
    __bf16* EO  = (__bf16*)((char*)d_ws + off);      off = align256(off + (size_t)E * 256 * 2);
    bool use_csr = (off <= ws_size);

    int nsample = E < 1024 ? E : 1024;
    hipLaunchKernelGGL(sniff_idx, dim3(1), dim3(256), 0, stream, ei, nsample, flag);

    int nprep = 256 * K1PAD + 2 * 256 * TWOF;
    hipLaunchKernelGGL(prep_weights, dim3((nprep + 255) / 256), dim3(256), 0, stream,
                       W1, W2, Wsm, Wvm, W1t, W2t, W3t);

    if (use_csr) {
        int nb = (N + 1023) / 1024;
        hipLaunchKernelGGL(zero_hist, dim3((N + 255) / 256), dim3(256), 0, stream, hist, N);
        hipLaunchKernelGGL(hist_k, dim3((E + 255) / 256), dim3(256), 0, stream, ei, flag, hist, E);
        hipLaunchKernelGGL(scan_a, dim3(nb), dim3(256), 0, stream, hist, loc, bsum, N);
        hipLaunchKernelGGL(scan_b, dim3(1), dim3(64), 0, stream, bsum, nb);
        hipLaunchKernelGGL(scan_c, dim3((N + 255) / 256), dim3(256), 0, stream, loc, bsum, rs, cursor, N, E);
        hipLaunchKernelGGL(scatter_k, dim3((E + 255) / 256), dim3(256), 0, stream, ei, flag, cursor, perm, E);

        hipLaunchKernelGGL(edge_kernel<1>, dim3(nblocks), dim3(512), 0, stream,
                           s, pos, ei, b1, b2, bsm, bvm, centers, widths,
                           W1t, W2t, W3t, flag, perm, EO, dirx, diry, dirz, out, N, E);

        hipLaunchKernelGGL(node_kernel, dim3((N + 3) / 4), dim3(256), 0, stream,
                           s, v, EO, dirx, diry, dirz, rs, out, N);
    } else {
        int nf4    = (N * FDIM) / 4;
        int total4 = N * FDIM;
        hipLaunchKernelGGL(init_out, dim3(8192), dim3(256), 0, stream,
                           (const float4*)s, (const float4*)v, (float4*)out, nf4, total4);
        hipLaunchKernelGGL(edge_kernel<0>, dim3(nblocks), dim3(512), 0, stream,
                           s, pos, ei, b1, b2, bsm, bvm, centers, widths,
                           W1t, W2t, W3t, flag, perm, EO, dirx, diry, dirz, out, N, E);
    }
}

// Round 4
// 711.863 us; speedup vs baseline: 1.3364x; 1.1709x over previous
//
#include <hip/hip_runtime.h>
#include <math.h>

#define FDIM   128
#define TWOF   256
#define NRBF_  20
#define INDIM  276
#define K1PAD  288          // INDIM padded to multiple of 32
#define XS     296          // shared-buffer row stride in bf16 (odd # of 16B chunks)
#define TE     64           // edges per workgroup (proven best: 4 blocks/CU, 4 indep blocks)

typedef __bf16 bf16x8 __attribute__((ext_vector_type(8)));
typedef __bf16 bf16x4 __attribute__((ext_vector_type(4)));
typedef float  f32x4  __attribute__((ext_vector_type(4)));
typedef float  f32x2  __attribute__((ext_vector_type(2)));
typedef unsigned int u32x4v __attribute__((ext_vector_type(4)));

__device__ inline float blo(unsigned p){ return __uint_as_float(p << 16); }
__device__ inline float bhi(unsigned p){ return __uint_as_float(p & 0xffff0000u); }

// ---------------- helper kernels ----------------

__global__ void sniff_idx(const int* __restrict__ ei, int nsample, int* __restrict__ flag) {
    __shared__ int any;
    if (threadIdx.x == 0) any = 0;
    __syncthreads();
    int nz = 0;
    for (int i = threadIdx.x; i < nsample; i += blockDim.x)
        nz |= (ei[2 * i + 1] != 0);
    if (nz) atomicOr(&any, 1);
    __syncthreads();
    if (threadIdx.x == 0) *flag = any;
}

__global__ void init_out(const float4* __restrict__ s4, const float4* __restrict__ v4,
                         float4* __restrict__ out4, int nf4, int total4) {
    for (int i = blockIdx.x * blockDim.x + threadIdx.x; i < total4;
         i += gridDim.x * blockDim.x)
        out4[i] = (i < nf4) ? s4[i] : v4[i - nf4];
}

__global__ void prep_weights(const float* __restrict__ W1, const float* __restrict__ W2,
                             const float* __restrict__ Ws, const float* __restrict__ Wv,
                             __bf16* __restrict__ W1t, __bf16* __restrict__ W2t,
                             __bf16* __restrict__ W3t) {
    int id = blockIdx.x * 256 + threadIdx.x;
    const int n1 = 256 * K1PAD;
    if (id < n1) {
        int n = id / K1PAD, k = id - n * K1PAD;
        W1t[id] = (k < INDIM) ? (__bf16)W1[k * TWOF + n] : (__bf16)0.f;
    } else if (id < n1 + 65536) {
        int j = id - n1; int n = j >> 8, k = j & 255;
        W2t[j] = (__bf16)W2[k * TWOF + n];
    } else if (id < n1 + 131072) {
        int j = id - n1 - 65536; int n = j >> 8, k = j & 255;
        W3t[j] = (n < FDIM) ? (__bf16)Ws[k * FDIM + n]
                            : (__bf16)Wv[k * FDIM + (n - FDIM)];
    }
}

// pre-convert s (N x 128 f32) -> bf16 once: halves gather traffic, removes cvt from hot loop
__global__ void prep_s(const float4* __restrict__ s4, bf16x8* __restrict__ s16, int n8) {
    int i = blockIdx.x * 256 + threadIdx.x;
    if (i >= n8) return;
    float4 a = s4[i * 2], b = s4[i * 2 + 1];
    bf16x8 o;
    o[0] = (__bf16)a.x; o[1] = (__bf16)a.y; o[2] = (__bf16)a.z; o[3] = (__bf16)a.w;
    o[4] = (__bf16)b.x; o[5] = (__bf16)b.y; o[6] = (__bf16)b.z; o[7] = (__bf16)b.w;
    s16[i] = o;
}

// ---------------- CSR build ----------------

__global__ void zero_hist(int* __restrict__ hist, int N) {
    int i = blockIdx.x * 256 + threadIdx.x;
    if (i < N) hist[i] = 0;
}

__global__ void hist_k(const int* __restrict__ ei, const int* __restrict__ flag,
                       int* __restrict__ hist, int E) {
    int e = blockIdx.x * 256 + threadIdx.x;
    if (e >= E) return;
    int dst = (*flag == 0) ? ei[2 * (E + e)] : ei[E + e];
    atomicAdd(&hist[dst], 1);
}

__global__ void scan_a(const int* __restrict__ hist, int* __restrict__ loc,
                       int* __restrict__ bsum, int N) {
    __shared__ int sums[256];
    int t = threadIdx.x;
    int base = blockIdx.x * 1024 + t * 4;
    int v0 = (base + 0 < N) ? hist[base + 0] : 0;
    int v1 = (base + 1 < N) ? hist[base + 1] : 0;
    int v2 = (base + 2 < N) ? hist[base + 2] : 0;
    int v3 = (base + 3 < N) ? hist[base + 3] : 0;
    int s = v0 + v1 + v2 + v3;
    sums[t] = s;
    __syncthreads();
    for (int off = 1; off < 256; off <<= 1) {
        int x = (t >= off) ? sums[t - off] : 0;
        __syncthreads();
        sums[t] += x;
        __syncthreads();
    }
    int excl = sums[t] - s;
    if (t == 255) bsum[blockIdx.x] = sums[255];
    if (base + 0 < N) loc[base + 0] = excl; excl += v0;
    if (base + 1 < N) loc[base + 1] = excl; excl += v1;
    if (base + 2 < N) loc[base + 2] = excl; excl += v2;
    if (base + 3 < N) loc[base + 3] = excl;
}

__global__ void scan_b(int* __restrict__ bsum, int nb) {
    if (threadIdx.x == 0 && blockIdx.x == 0) {
        int run = 0;
        for (int i = 0; i < nb; ++i) { int v = bsum[i]; bsum[i] = run; run += v; }
    }
}

__global__ void scan_c(const int* __restrict__ loc, const int* __restrict__ bsum,
                       int* __restrict__ rs, int* __restrict__ cursor, int N, int E) {
    int i = blockIdx.x * 256 + threadIdx.x;
    if (i < N) {
        int v = loc[i] + bsum[i >> 10];
        rs[i] = v; cursor[i] = v;
    }
    if (i == 0) rs[N] = E;
}

// store edge -> CSR slot (perm), not slot -> edge
__global__ void scatter_k(const int* __restrict__ ei, const int* __restrict__ flag,
                          int* __restrict__ cursor, int* __restrict__ perm, int E) {
    int e = blockIdx.x * 256 + threadIdx.x;
    if (e >= E) return;
    int dst = (*flag == 0) ? ei[2 * (E + e)] : ei[E + e];
    int pos = atomicAdd(&cursor[dst], 1);
    perm[e] = pos;
}

// ---------------- main edge kernel ----------------
// Single LDS buffer Sb holds X (L1 input), then H (L1/L2 output), then EO staging.
// TE=64 / 256 threads / 4 waves, 4 blocks/CU (39.9KB LDS): proven best config.
// This round: phase-A spread over all 256 threads (4/edge), bf16 s-gather,
// setprio around MFMA clusters.

template<int CSR>
__launch_bounds__(256, 4)
__global__ void edge_kernel(const __bf16* __restrict__ s16,
                            const float* __restrict__ pos,
                            const int* __restrict__ ei,
                            const float* __restrict__ b1, const float* __restrict__ b2,
                            const float* __restrict__ bsm, const float* __restrict__ bvm,
                            const float* __restrict__ centers, const float* __restrict__ widths,
                            const __bf16* __restrict__ W1t, const __bf16* __restrict__ W2t,
                            const __bf16* __restrict__ W3t,
                            const int* __restrict__ flag,
                            const int* __restrict__ perm,
                            __bf16* __restrict__ EO,
                            float* __restrict__ dirx, float* __restrict__ diry,
                            float* __restrict__ dirz,
                            float* __restrict__ out, int N, int E) {
    __shared__ __align__(16) __bf16 Sb[TE][XS];
    __shared__ float sdir[3][TE];
    __shared__ int ssrc[TE], sdst[TE], svalid[TE], sperm[TE];

    const int t    = threadIdx.x;
    const int lane = t & 63;
    const int wave = t >> 6;
    const int e0   = blockIdx.x * TE;
    const int i64  = (*flag == 0);

    // ---- Phase A: per-edge prep, 4 threads per edge (parallel RBF + short dep chains)
    {
        const int eL  = t >> 2;      // 0..63 local edge
        const int sub = t & 3;       // 0..3 RBF slice
        int e = e0 + eL;
        int valid = (e < E);
        int srcn = 0, dstn = 0;
        if (valid) {
            if (i64) { srcn = ei[2 * e]; dstn = ei[2 * (E + e)]; }
            else     { srcn = ei[e];     dstn = ei[E + e]; }
        }
        float rx = pos[dstn * 3 + 0] - pos[srcn * 3 + 0];
        float ry = pos[dstn * 3 + 1] - pos[srcn * 3 + 1];
        float rz = pos[dstn * 3 + 2] - pos[srcn * 3 + 2];
        float dist = sqrtf(rx * rx + ry * ry + rz * rz);
        if (sub == 0) {
            ssrc[eL] = srcn; sdst[eL] = dstn; svalid[eL] = valid;
            float inv = dist > 0.f ? 1.f / dist : 0.f;
            float dx = rx * inv, dy = ry * inv, dz = rz * inv;
            sdir[0][eL] = dx; sdir[1][eL] = dy; sdir[2][eL] = dz;
            int p = 0;
            if (CSR && valid) {
                p = perm[e];
                __builtin_nontemporal_store(dx, &dirx[p]);
                __builtin_nontemporal_store(dy, &diry[p]);
                __builtin_nontemporal_store(dz, &dirz[p]);
            }
            sperm[eL] = p;
        }
#pragma unroll
        for (int k8 = 0; k8 < 8; ++k8) {
            int k = sub * 8 + k8;
            float val = 0.f;
            if (k < NRBF_) {
                float u = (dist - centers[k]) / (widths[k] + 1e-8f);
                val = __expf(-u * u);
            }
            Sb[eL][TWOF + k] = (__bf16)val;
        }
    }
    __syncthreads();

    // ---- Phase B: gather s16[src]/s16[dst] -> X cols 0..255 (bf16, 16B/lane)
    {
        const int pair = lane >> 5;        // which of 2 edges this iter
        const int half = (lane >> 4) & 1;  // 0: src, 1: dst
        const int q    = lane & 15;        // 16-byte chunk
        const bf16x8* s8 = (const bf16x8*)s16;
#pragma unroll
        for (int i = 0; i < 8; ++i) {
            int e = wave * 16 + i * 2 + pair;
            int node = half ? sdst[e] : ssrc[e];
            bf16x8 x = s8[node * 16 + q];
            *(bf16x8*)&Sb[e][half * FDIM + q * 8] = x;
        }
    }
    __syncthreads();

    const int l15 = lane & 15;
    const int kg  = (lane >> 4) * 8;
    const int nbase = wave * 64;

    f32x4 acc[4][4];

    // ================= Layer 1: K=288 (reads X) =================
#pragma unroll
    for (int et = 0; et < 4; ++et)
#pragma unroll
        for (int nt = 0; nt < 4; ++nt) acc[et][nt] = (f32x4)0.f;
    {
        const __bf16* bp[4];
#pragma unroll
        for (int nt = 0; nt < 4; ++nt)
            bp[nt] = &W1t[(size_t)(nbase + nt * 16 + l15) * K1PAD + kg];
        bf16x8 bcur[4];
#pragma unroll
        for (int nt = 0; nt < 4; ++nt) bcur[nt] = *(const bf16x8*)bp[nt];
        __builtin_amdgcn_s_setprio(1);
#pragma unroll
        for (int kc = 0; kc < K1PAD; kc += 32) {
            bf16x8 bnxt[4];
            if (kc + 32 < K1PAD) {
#pragma unroll
                for (int nt = 0; nt < 4; ++nt)
                    bnxt[nt] = *(const bf16x8*)(bp[nt] + kc + 32);
            }
            bf16x8 a[4];
#pragma unroll
            for (int et = 0; et < 4; ++et)
                a[et] = *(const bf16x8*)&Sb[et * 16 + l15][kc + kg];
#pragma unroll
            for (int nt = 0; nt < 4; ++nt)
#pragma unroll
                for (int et = 0; et < 4; ++et)
                    acc[et][nt] = __builtin_amdgcn_mfma_f32_16x16x32_bf16(a[et], bcur[nt], acc[et][nt], 0, 0, 0);
#pragma unroll
            for (int nt = 0; nt < 4; ++nt) bcur[nt] = bnxt[nt];
        }
        __builtin_amdgcn_s_setprio(0);
    }
    __syncthreads();   // all X reads complete before H overwrites the buffer
#pragma unroll
    for (int nt = 0; nt < 4; ++nt) {
        int n = nbase + nt * 16 + l15;
        float bb = b1[n];
#pragma unroll
        for (int et = 0; et < 4; ++et)
#pragma unroll
            for (int r = 0; r < 4; ++r) {
                int m = et * 16 + (lane >> 4) * 4 + r;
                float h = acc[et][nt][r] + bb;
                Sb[m][n] = (__bf16)(h * __builtin_amdgcn_rcpf(1.f + __expf(-h)));
            }
    }
    __syncthreads();

    // ================= Layer 2: K=256 (reads H, rewrites H) =================
#pragma unroll
    for (int et = 0; et < 4; ++et)
#pragma unroll
        for (int nt = 0; nt < 4; ++nt) acc[et][nt] = (f32x4)0.f;
    {
        const __bf16* bp[4];
#pragma unroll
        for (int nt = 0; nt < 4; ++nt)
            bp[nt] = &W2t[(size_t)(nbase + nt * 16 + l15) * TWOF + kg];
        bf16x8 bcur[4];
#pragma unroll
        for (int nt = 0; nt < 4; ++nt) bcur[nt] = *(const bf16x8*)bp[nt];
        __builtin_amdgcn_s_setprio(1);
#pragma unroll
        for (int kc = 0; kc < TWOF; kc += 32) {
            bf16x8 bnxt[4];
            if (kc + 32 < TWOF) {
#pragma unroll
                for (int nt = 0; nt < 4; ++nt)
                    bnxt[nt] = *(const bf16x8*)(bp[nt] + kc + 32);
            }
            bf16x8 a[4];
#pragma unroll
            for (int et = 0; et < 4; ++et)
                a[et] = *(const bf16x8*)&Sb[et * 16 + l15][kc + kg];
#pragma unroll
            for (int nt = 0; nt < 4; ++nt)
#pragma unroll
                for (int et = 0; et < 4; ++et)
                    acc[et][nt] = __builtin_amdgcn_mfma_f32_16x16x32_bf16(a[et], bcur[nt], acc[et][nt], 0, 0, 0);
#pragma unroll
            for (int nt = 0; nt < 4; ++nt) bcur[nt] = bnxt[nt];
        }
        __builtin_amdgcn_s_setprio(0);
    }
    __syncthreads();   // all h1 reads complete before overwrite
#pragma unroll
    for (int nt = 0; nt < 4; ++nt) {
        int n = nbase + nt * 16 + l15;
        float bb = b2[n];
#pragma unroll
        for (int et = 0; et < 4; ++et)
#pragma unroll
            for (int r = 0; r < 4; ++r) {
                int m = et * 16 + (lane >> 4) * 4 + r;
                float h = acc[et][nt][r] + bb;
                Sb[m][n] = (__bf16)(h * __builtin_amdgcn_rcpf(1.f + __expf(-h)));
            }
    }
    __syncthreads();

    // ================= Layer 3: K=256 (reads H) =================
#pragma unroll
    for (int et = 0; et < 4; ++et)
#pragma unroll
        for (int nt = 0; nt < 4; ++nt) acc[et][nt] = (f32x4)0.f;
    {
        const __bf16* bp[4];
#pragma unroll
        for (int nt = 0; nt < 4; ++nt) {
            int rowbase = ((nt >= 2) ? FDIM : 0) + wave * 32 + (nt & 1) * 16 + l15;
            bp[nt] = &W3t[(size_t)rowbase * TWOF + kg];
        }
        bf16x8 bcur[4];
#pragma unroll
        for (int nt = 0; nt < 4; ++nt) bcur[nt] = *(const bf16x8*)bp[nt];
        __builtin_amdgcn_s_setprio(1);
#pragma unroll
        for (int kc = 0; kc < TWOF; kc += 32) {
            bf16x8 bnxt[4];
            if (kc + 32 < TWOF) {
#pragma unroll
                for (int nt = 0; nt < 4; ++nt)
                    bnxt[nt] = *(const bf16x8*)(bp[nt] + kc + 32);
            }
            bf16x8 a[4];
#pragma unroll
            for (int et = 0; et < 4; ++et)
                a[et] = *(const bf16x8*)&Sb[et * 16 + l15][kc + kg];
#pragma unroll
            for (int nt = 0; nt < 4; ++nt)
#pragma unroll
                for (int et = 0; et < 4; ++et)
                    acc[et][nt] = __builtin_amdgcn_mfma_f32_16x16x32_bf16(a[et], bcur[nt], acc[et][nt], 0, 0, 0);
#pragma unroll
            for (int nt = 0; nt < 4; ++nt) bcur[nt] = bnxt[nt];
        }
        __builtin_amdgcn_s_setprio(0);
    }

    float b3v[4];
#pragma unroll
    for (int nt = 0; nt < 4; ++nt) {
        int n = wave * 32 + (nt & 1) * 16 + l15;
        b3v[nt] = (nt < 2) ? bsm[n] : bvm[n];
    }

    if (CSR) {
        __syncthreads();   // all H reads complete before EO staging overwrites buffer
        __bf16 (*EOs)[XS] = (__bf16(*)[XS])(&Sb[0][0]);
#pragma unroll
        for (int nt = 0; nt < 4; ++nt) {
            int col = ((nt >= 2) ? FDIM : 0) + wave * 32 + (nt & 1) * 16 + l15;
            float bb = b3v[nt];
#pragma unroll
            for (int et = 0; et < 4; ++et)
#pragma unroll
                for (int r = 0; r < 4; ++r) {
                    int m = et * 16 + (lane >> 4) * 4 + r;
                    EOs[m][col] = (__bf16)(acc[et][nt][r] + bb);
                }
        }
        __syncthreads();
        u32x4v* dst4 = (u32x4v*)EO;
#pragma unroll
        for (int j = 0; j < 8; ++j) {
            int flat = j * 256 + t;          // 0..2047
            int row = flat >> 5, col = flat & 31;
            if (!svalid[row]) continue;
            __builtin_nontemporal_store(*(const u32x4v*)&EOs[row][col * 8],
                                        &dst4[(size_t)sperm[row] * 32 + col]);
        }
    } else {
        float* outs = out;
        float* outv = out + (size_t)N * FDIM;
#pragma unroll
        for (int et = 0; et < 4; ++et) {
#pragma unroll
            for (int r = 0; r < 4; ++r) {
                int m = et * 16 + (lane >> 4) * 4 + r;
                if (!svalid[m]) continue;
                int dst = sdst[m];
                float dx = sdir[0][m], dy = sdir[1][m], dz = sdir[2][m];
#pragma unroll
                for (int nt = 0; nt < 4; ++nt) {
                    int n = wave * 32 + (nt & 1) * 16 + l15;
                    float val = acc[et][nt][r] + b3v[nt];
                    if (nt < 2) {
                        atomicAdd(&outs[dst * FDIM + n], val);
                    } else {
                        int base = dst * 3 * FDIM + n;
                        atomicAdd(&outv[base],            dx * val);
                        atomicAdd(&outv[base + FDIM],     dy * val);
                        atomicAdd(&outv[base + 2 * FDIM], dz * val);
                    }
                }
            }
        }
    }
}

// ---------------- node aggregation: fully streaming (EO/dir pre-sorted) ----------------

__launch_bounds__(256)
__global__ void node_kernel(const float* __restrict__ s, const float* __restrict__ v,
                            const __bf16* __restrict__ EO,
                            const float* __restrict__ dirx, const float* __restrict__ diry,
                            const float* __restrict__ dirz,
                            const int* __restrict__ rs,
                            float* __restrict__ out, int N) {
    int wave = threadIdx.x >> 6, lane = threadIdx.x & 63;
    int n = blockIdx.x * 4 + wave;
    if (n >= N) return;
    int beg = rs[n], end = rs[n + 1];

    float a0 = 0.f, a1 = 0.f;
    float vx0 = 0.f, vx1 = 0.f, vy0 = 0.f, vy1 = 0.f, vz0 = 0.f, vz1 = 0.f;
    const unsigned* EO32 = (const unsigned*)EO;

#pragma unroll 2
    for (int i = beg; i < end; ++i) {
        unsigned pds = __builtin_nontemporal_load(&EO32[(size_t)i * 128 + lane]);
        unsigned pvm = __builtin_nontemporal_load(&EO32[(size_t)i * 128 + 64 + lane]);
        float dx = __builtin_nontemporal_load(&dirx[i]);
        float dy = __builtin_nontemporal_load(&diry[i]);
        float dz = __builtin_nontemporal_load(&dirz[i]);
        float d0 = blo(pds), d1 = bhi(pds);
        float m0 = blo(pvm), m1 = bhi(pvm);
        a0 += d0; a1 += d1;
        vx0 = fmaf(dx, m0, vx0); vx1 = fmaf(dx, m1, vx1);
        vy0 = fmaf(dy, m0, vy0); vy1 = fmaf(dy, m1, vy1);
        vz0 = fmaf(dz, m0, vz0); vz1 = fmaf(dz, m1, vz1);
    }

    f32x2 sv = *((const f32x2*)&s[(size_t)n * FDIM] + lane);
    f32x2 o0 = { sv.x + a0, sv.y + a1 };
    __builtin_nontemporal_store(o0, (f32x2*)&out[(size_t)n * FDIM] + lane);

    const float* vb = &v[(size_t)n * 3 * FDIM];
    float* ovb = &out[(size_t)N * FDIM + (size_t)n * 3 * FDIM];
    f32x2 vv;
    vv = *((const f32x2*)vb + lane);
    f32x2 ox = { vv.x + vx0, vv.y + vx1 };
    __builtin_nontemporal_store(ox, (f32x2*)ovb + lane);
    vv = *((const f32x2*)(vb + FDIM) + lane);
    f32x2 oy = { vv.x + vy0, vv.y + vy1 };
    __builtin_nontemporal_store(oy, (f32x2*)(ovb + FDIM) + lane);
    vv = *((const f32x2*)(vb + 2 * FDIM) + lane);
    f32x2 oz = { vv.x + vz0, vv.y + vz1 };
    __builtin_nontemporal_store(oz, (f32x2*)(ovb + 2 * FDIM) + lane);
}

// ---------------- host ----------------

static inline size_t align256(size_t x) { return (x + 255) & ~(size_t)255; }

extern "C" void kernel_launch(void* const* d_in, const int* in_sizes, int n_in,
                              void* d_out, int out_size, void* d_ws, size_t ws_size,
                              hipStream_t stream) {
    const float* s   = (const float*)d_in[0];
    const float* v   = (const float*)d_in[1];
    const float* pos = (const float*)d_in[2];
    const int*   ei  = (const int*)d_in[3];
    const float* W1  = (const float*)d_in[4];
    const float* b1  = (const float*)d_in[5];
    const float* W2  = (const float*)d_in[6];
    const float* b2  = (const float*)d_in[7];
    const float* Wsm = (const float*)d_in[8];
    const float* bsm = (const float*)d_in[9];
    const float* Wvm = (const float*)d_in[10];
    const float* bvm = (const float*)d_in[11];
    const float* centers = (const float*)d_in[12];
    const float* widths  = (const float*)d_in[13];
    float* out = (float*)d_out;

    int N = in_sizes[0] / FDIM;
    int E = in_sizes[3] / 2;
    int nblocks = (E + TE - 1) / TE;

    // workspace layout
    size_t off = 0;
    int* flag = (int*)((char*)d_ws + off);           off = align256(off + 4);
    __bf16* W1t = (__bf16*)((char*)d_ws + off);      off = align256(off + (size_t)256 * K1PAD * 2);
    __bf16* W2t = (__bf16*)((char*)d_ws + off);      off = align256(off + (size_t)256 * TWOF * 2);
    __bf16* W3t = (__bf16*)((char*)d_ws + off);      off = align256(off + (size_t)256 * TWOF * 2);
    __bf16* s16 = (__bf16*)((char*)d_ws + off);      off = align256(off + (size_t)N * FDIM * 2);
    int* hist   = (int*)((char*)d_ws + off);         off = align256(off + (size_t)N * 4);
    int* loc    = (int*)((char*)d_ws + off);         off = align256(off + (size_t)N * 4);
    int* bsum   = (int*)((char*)d_ws + off);         off = align256(off + 1024);
    int* rs     = (int*)((char*)d_ws + off);         off = align256(off + (size_t)(N + 1) * 4);
    int* cursor = (int*)((char*)d_ws + off);         off = align256(off + (size_t)N * 4);
    int* perm   = (int*)((char*)d_ws + off);         off = align256(off + (size_t)E * 4);
    float* dirx = (float*)((char*)d_ws + off);       off = align256(off + (size_t)E * 4);
    float* diry = (float*)((char*)d_ws + off);       off = align256(off + (size_t)E * 4);
    float* dirz = (float*)((char*)d_ws + off);       off = align256(off + (size_t)E * 4);
    __bf16* EO  = (__bf16*)((char*)d_ws + off);      off = align256(off + (size_t)E * 256 * 2);
    bool use_csr = (off <= ws_size);

    int nsample = E < 1024 ? E : 1024;
    hipLaunchKernelGGL(sniff_idx, dim3(1), dim3(256), 0, stream, ei, nsample, flag);

    int nprep = 256 * K1PAD + 2 * 256 * TWOF;
    hipLaunchKernelGGL(prep_weights, dim3((nprep + 255) / 256), dim3(256), 0, stream,
                       W1, W2, Wsm, Wvm, W1t, W2t, W3t);

    int n8 = (N * FDIM) / 8;
    hipLaunchKernelGGL(prep_s, dim3((n8 + 255) / 256), dim3(256), 0, stream,
                       (const float4*)s, (bf16x8*)s16, n8);

    if (use_csr) {
        int nb = (N + 1023) / 1024;
        hipLaunchKernelGGL(zero_hist, dim3((N + 255) / 256), dim3(256), 0, stream, hist, N);
        hipLaunchKernelGGL(hist_k, dim3((E + 255) / 256), dim3(256), 0, stream, ei, flag, hist, E);
        hipLaunchKernelGGL(scan_a, dim3(nb), dim3(256), 0, stream, hist, loc, bsum, N);
        hipLaunchKernelGGL(scan_b, dim3(1), dim3(64), 0, stream, bsum, nb);
        hipLaunchKernelGGL(scan_c, dim3((N + 255) / 256), dim3(256), 0, stream, loc, bsum, rs, cursor, N, E);
        hipLaunchKernelGGL(scatter_k, dim3((E + 255) / 256), dim3(256), 0, stream, ei, flag, cursor, perm, E);

        hipLaunchKernelGGL(edge_kernel<1>, dim3(nblocks), dim3(256), 0, stream,
                           s16, pos, ei, b1, b2, bsm, bvm, centers, widths,
                           W1t, W2t, W3t, flag, perm, EO, dirx, diry, dirz, out, N, E);

        hipLaunchKernelGGL(node_kernel, dim3((N + 3) / 4), dim3(256), 0, stream,
                           s, v, EO, dirx, diry, dirz, rs, out, N);
    } else {
        int nf4    = (N * FDIM) / 4;
        int total4 = N * FDIM;
        hipLaunchKernelGGL(init_out, dim3(8192), dim3(256), 0, stream,
                           (const float4*)s, (const float4*)v, (float4*)out, nf4, total4);
        hipLaunchKernelGGL(edge_kernel<0>, dim3(nblocks), dim3(256), 0, stream,
                           s16, pos, ei, b1, b2, bsm, bvm, centers, widths,
                           W1t, W2t, W3t, flag, perm, EO, dirx, diry, dirz, out, N, E);
    }
}